// Round 12
// baseline (231.992 us; speedup 1.0000x reference)
//
#include <hip/hip_runtime.h>

#define OBS 128
#define HID 64
#define ACT 32
#define TT  128
#define BB  4096

typedef __attribute__((ext_vector_type(8))) short bf16x8;  // 8 bf16 (4 VGPRs)
typedef __attribute__((ext_vector_type(4))) float f32x4;

// tanh(v) = 1 - 2/(exp(2v)+1); exact at +-inf, ~1e-6 rel error (v_exp + v_rcp)
__device__ __forceinline__ float fast_tanh(float v) {
  const float e = __expf(2.0f * v);
  return 1.0f - 2.0f * __builtin_amdgcn_rcpf(e + 1.0f);
}

// f32 -> bf16 bits, round-to-nearest-even (used host-side of the hot loops:
// prep kernel + capture's x/b2 conversion)
__device__ __forceinline__ short f2bf(float f) {
  const unsigned u = __float_as_uint(f);
  return (short)((u + 0x7FFFu + ((u >> 16) & 1u)) >> 16);
}

// HW packed f32x2 -> bf16x2 (RNE), gfx950; no builtin -> inline asm (T12/m240)
__device__ __forceinline__ unsigned cvtpk(float lo, float hi) {
  unsigned r;
  asm("v_cvt_pk_bf16_f32 %0, %1, %2" : "=v"(r) : "v"(lo), "v"(hi));
  return r;
}

// pack two f32x4 (C/D-layout register quads) into one bf16x8 B-fragment
// via 4 HW cvt_pk (replaces 32 VALU ops of software rounding)
__device__ __forceinline__ bf16x8 cvt8(const f32x4 s0, const f32x4 s1) {
  union { bf16x8 f; unsigned u[4]; } z;
  z.u[0] = cvtpk(s0[0], s0[1]); z.u[1] = cvtpk(s0[2], s0[3]);
  z.u[2] = cvtpk(s1[0], s1[1]); z.u[3] = cvtpk(s1[2], s1[3]);
  return z.f;
}

// pack [float4, float4] -> bf16x8 (a-fragment)
__device__ __forceinline__ bf16x8 cvt8f(const float4 lo, const float4 hi) {
  union { bf16x8 f; unsigned u[4]; } z;
  z.u[0] = cvtpk(lo.x, lo.y); z.u[1] = cvtpk(lo.z, lo.w);
  z.u[2] = cvtpk(hi.x, hi.y); z.u[3] = cvtpk(hi.z, hi.w);
  return z.f;
}

// ---------------------------------------------------------------------------
// Prep: pre-convert ALL weights into fragment-ordered bf16 in d_ws (verbatim
// from round 6). Fragment map (64 lanes x 16 B each):
//   [0,16)  capture w1t[m=f>>2][kk=f&3]          std k-map on Wc1
//   [16,24) capture w2t[(f-16)>>1][(f-16)&1]     custom k-map on Wc2
//   [24,32) recur   w1h[(f-24)>>1][(f-24)&1]     custom k-map on Wp1 (h rows)
//   [32,40) recur   w2t[(f-32)>>1][(f-32)&1]     custom k-map on Wp2
//   [40,44) recur   w1a[f-40]                    std a-map on Wp1 rows HID+
// ---------------------------------------------------------------------------
__global__ void prep_weights(const float* __restrict__ Wc1,
                             const float* __restrict__ Wc2,
                             const float* __restrict__ Wp1,
                             const float* __restrict__ Wp2,
                             short* __restrict__ ws)
{
  const int idx = blockIdx.x * blockDim.x + threadIdx.x;  // 0..(44*64-1)
  if (idx >= 44 * 64) return;
  const int f = idx >> 6, lane = idx & 63;
  const int r = lane & 15, G = lane >> 4;
  short o[8];
  if (f < 16) {
    const int m = f >> 2, kk = f & 3;  // std: k = 32kk + 8G + j
#pragma unroll
    for (int j = 0; j < 8; ++j)
      o[j] = f2bf(Wc1[(kk * 32 + 8 * G + j) * HID + 16 * m + r]);
  } else if (f < 40) {
    const int q = (f < 24) ? (f - 16) : (f < 32) ? (f - 24) : (f - 32);
    const float* W = (f < 24) ? Wc2 : (f < 32) ? Wp1 : Wp2;
    const int m = q >> 1, kk = q & 1;  // custom k-map (matches lane-resident C/D)
#pragma unroll
    for (int j = 0; j < 8; ++j) {
      const int k = (j < 4) ? (32 * kk + 4 * G + j)
                            : (32 * kk + 16 + 4 * G + (j - 4));
      o[j] = f2bf(W[k * HID + 16 * m + r]);
    }
  } else {
    const int m = f - 40;  // a-part, std map: k = HID + 8G + j
#pragma unroll
    for (int j = 0; j < 8; ++j)
      o[j] = f2bf(Wp1[(HID + 8 * G + j) * HID + 16 * m + r]);
  }
  bf16x8 v;
#pragma unroll
  for (int j = 0; j < 8; ++j) v[j] = o[j];
  *(bf16x8*)(ws + (size_t)idx * 8) = v;
}

// ---------------------------------------------------------------------------
// Phase 1: capture — BYTE-IDENTICAL to round 9 (controlled variable; HBM-
// bound at ~64-75 us with 2 blocks/CU, weights deterministic in LDS).
// ---------------------------------------------------------------------------
__global__ __launch_bounds__(256, 2) void capture_lds(
    const float* __restrict__ x,
    const short* __restrict__ wsw,
    const float* __restrict__ bc1, const float* __restrict__ bc2,
    float* __restrict__ capt)
{
  __shared__ bf16x8 wl[24 * 64];  // 24.5 KB fragment table

  const int tid  = threadIdx.x;
  const int lane = tid & 63;
  const int r    = lane & 15;   // tile-row (N dim)
  const int G    = lane >> 4;   // k-group
  const int wave = blockIdx.x * 4 + (tid >> 6);
  const int nwaves = gridDim.x * 4;

  // stage fragment table (coalesced 16 B/thread x 6 iters)
  for (int s = tid; s < 24 * 64; s += 256)
    wl[s] = ((const bf16x8*)wsw)[s];
  __syncthreads();

  f32x4 bias1[4], bias2[4];
#pragma unroll
  for (int m = 0; m < 4; ++m) {
    bias1[m] = *(const f32x4*)(bc1 + 16 * m + 4 * G);
    bias2[m] = *(const f32x4*)(bc2 + 16 * m + 4 * G);
  }

  for (int tile = wave; tile < (TT * BB) / 16; tile += nwaves) {
    // structural fence: weight ds_reads cannot be hoisted/CSE'd across
    // iterations -> per-iter LDS reads, deterministic codegen
    asm volatile("" ::: "memory");

    const float* xrow = x + ((size_t)tile * 16 + r) * OBS;
    bf16x8 xa[4];
#pragma unroll
    for (int kk = 0; kk < 4; ++kk) {
      const float4 lo = *(const float4*)(xrow + kk * 32 + 8 * G);
      const float4 hi = *(const float4*)(xrow + kk * 32 + 8 * G + 4);
      bf16x8 f;
      f[0] = f2bf(lo.x); f[1] = f2bf(lo.y); f[2] = f2bf(lo.z); f[3] = f2bf(lo.w);
      f[4] = f2bf(hi.x); f[5] = f2bf(hi.y); f[6] = f2bf(hi.z); f[7] = f2bf(hi.w);
      xa[kk] = f;
    }

    float um[4][4];
#pragma unroll
    for (int m = 0; m < 4; ++m) {
      f32x4 acc = bias1[m];
#pragma unroll
      for (int kk = 0; kk < 4; ++kk)
        acc = __builtin_amdgcn_mfma_f32_16x16x32_bf16(wl[(m * 4 + kk) * 64 + lane],
                                                      xa[kk], acc, 0, 0, 0);
#pragma unroll
      for (int q = 0; q < 4; ++q) um[m][q] = fast_tanh(acc[q]);
    }

    bf16x8 b2[2];
#pragma unroll
    for (int kk = 0; kk < 2; ++kk) {
      bf16x8 f;
#pragma unroll
      for (int j = 0; j < 4; ++j) f[j]     = f2bf(um[2 * kk][j]);
#pragma unroll
      for (int j = 0; j < 4; ++j) f[4 + j] = f2bf(um[2 * kk + 1][j]);
      b2[kk] = f;
    }

    float* crow = capt + ((size_t)tile * 16 + r) * HID;
#pragma unroll
    for (int m = 0; m < 4; ++m) {
      f32x4 acc = bias2[m];
#pragma unroll
      for (int kk = 0; kk < 2; ++kk)
        acc = __builtin_amdgcn_mfma_f32_16x16x32_bf16(wl[(16 + m * 2 + kk) * 64 + lane],
                                                      b2[kk], acc, 0, 0, 0);
      float4 o;
      o.x = fast_tanh(acc[0]); o.y = fast_tanh(acc[1]);
      o.z = fast_tanh(acc[2]); o.w = fast_tanh(acc[3]);
      *(float4*)(crow + 16 * m + 4 * G) = o;
    }
  }
}

// ---------------------------------------------------------------------------
// Phase 2: recurrence — MONOLITH (r4 structure: one wave owns 16 rows for the
// whole scan, h stays in registers, ZERO barriers) + the two proven fixes:
//  - weights in LDS with per-step fence (r9's determinism fix: the r4/r5
//    regalloc lottery is structurally gone; 20 ds_read_b128/step, issue
//    ~40 cyc, latency compiler-scheduled)
//  - v_cvt_pk_bf16_f32 packing (160 VALU ops/step -> 20 instrs)
// vs r7/r9's 4-wave m-split: that design put 2 barrier round-trips + 2 LDS
// round-trips INSIDE the serial h-chain (~2600 cyc/step -> ~140 us). The
// monolith is issue-bound instead: ~1000 cyc/step ~= its HBM share.
// Grid: 256 blocks x 64 threads (1 wave/CU).
// ---------------------------------------------------------------------------
#define R_LOADS(t, Z, AL, AH, GV)                                   \
  do {                                                              \
    const size_t rb = (size_t)(t) * BB + row;                       \
    const float* zp = z1buf + rb * HID;                             \
    Z##0 = *(const f32x4*)(zp + 4 * G);                             \
    Z##1 = *(const f32x4*)(zp + 16 + 4 * G);                        \
    Z##2 = *(const f32x4*)(zp + 32 + 4 * G);                        \
    Z##3 = *(const f32x4*)(zp + 48 + 4 * G);                        \
    const float* ap = a + rb * ACT + 8 * G;                         \
    AL = *(const float4*)(ap);                                      \
    AH = *(const float4*)(ap + 4);                                  \
    GV = g[rb];                                                     \
  } while (0)

#define R_COMPUTE(t, Z0, Z1, Z2, Z3, AL, AH, GV)                               \
  do {                                                                         \
    asm volatile("" ::: "memory");  /* per-step fence: fresh weight ds_reads */\
    const bf16x8 ab = cvt8f(AL, AH);                                           \
    f32x4 um[4];                                                               \
    _Pragma("unroll")                                                          \
    for (int m = 0; m < 4; ++m) {                                              \
      f32x4 acc = bias1[m];                                                    \
      acc = __builtin_amdgcn_mfma_f32_16x16x32_bf16(wl[(2 * m + 0) * 64 + lane], hb0, acc, 0, 0, 0); \
      acc = __builtin_amdgcn_mfma_f32_16x16x32_bf16(wl[(2 * m + 1) * 64 + lane], hb1, acc, 0, 0, 0); \
      acc = __builtin_amdgcn_mfma_f32_16x16x32_bf16(wl[(16 + m) * 64 + lane], ab, acc, 0, 0, 0); \
      f32x4 u;                                                                 \
      u[0] = fast_tanh(acc[0]); u[1] = fast_tanh(acc[1]);                      \
      u[2] = fast_tanh(acc[2]); u[3] = fast_tanh(acc[3]);                      \
      um[m] = u;                                                               \
    }                                                                          \
    const bf16x8 ub0 = cvt8(um[0], um[1]);                                     \
    const bf16x8 ub1 = cvt8(um[2], um[3]);                                     \
    const size_t ob = ((size_t)(t) * BB + row) * HID;                          \
    _Pragma("unroll")                                                          \
    for (int m = 0; m < 4; ++m) {                                              \
      f32x4 acc = bias2[m];                                                    \
      acc = __builtin_amdgcn_mfma_f32_16x16x32_bf16(wl[(8 + 2 * m + 0) * 64 + lane], ub0, acc, 0, 0, 0); \
      acc = __builtin_amdgcn_mfma_f32_16x16x32_bf16(wl[(8 + 2 * m + 1) * 64 + lane], ub1, acc, 0, 0, 0); \
      const f32x4 zz = (m == 0) ? Z0 : (m == 1) ? Z1 : (m == 2) ? Z2 : Z3;     \
      f32x4 hn;                                                                \
      hn[0] = fmaf(GV, fast_tanh(acc[0]) - zz[0], zz[0]);                      \
      hn[1] = fmaf(GV, fast_tanh(acc[1]) - zz[1], zz[1]);                      \
      hn[2] = fmaf(GV, fast_tanh(acc[2]) - zz[2], zz[2]);                      \
      hn[3] = fmaf(GV, fast_tanh(acc[3]) - zz[3], zz[3]);                      \
      hm[m] = hn;                                                              \
      *(f32x4*)(outs + ob + 16 * m + 4 * G) = hn;                              \
    }                                                                          \
    hb0 = cvt8(hm[0], hm[1]);                                                  \
    hb1 = cvt8(hm[2], hm[3]);                                                  \
  } while (0)

__global__ __launch_bounds__(64, 1) void recur_mono(
    const float* __restrict__ h0,
    const float* __restrict__ g,
    const float* __restrict__ a,
    const short* __restrict__ wsw,
    const float* __restrict__ bp1, const float* __restrict__ bp2,
    const float* __restrict__ z1buf,
    float* __restrict__ outs, float* __restrict__ hlast)
{
  __shared__ bf16x8 wl[20 * 64];  // 20 KB: recur frags 24..43 of ws
  //   local 0..7  = w1h[m][kk] (m*2+kk)
  //   local 8..15 = w2t[m][kk]
  //   local 16..19= w1a[m]

  const int lane = threadIdx.x & 63;
  const int r    = lane & 15;
  const int G    = lane >> 4;
  const int row  = blockIdx.x * 16 + r;   // batch row owned by this lane

  // stage weight fragments (single wave, 20 coalesced 16 B copies; no
  // barrier needed — same-wave ds_write->ds_read ordered via lgkmcnt)
  {
    const bf16x8* wf = (const bf16x8*)wsw;
#pragma unroll
    for (int f = 0; f < 20; ++f)
      wl[f * 64 + lane] = wf[(24 + f) * 64 + lane];
  }

  f32x4 bias1[4], bias2[4];
#pragma unroll
  for (int m = 0; m < 4; ++m) {
    bias1[m] = *(const f32x4*)(bp1 + 16 * m + 4 * G);
    bias2[m] = *(const f32x4*)(bp2 + 16 * m + 4 * G);
  }

  // ---- h state in C/D layout ----
  f32x4 hm[4];
#pragma unroll
  for (int m = 0; m < 4; ++m)
    hm[m] = *(const f32x4*)(h0 + (size_t)row * HID + 16 * m + 4 * G);
  bf16x8 hb0 = cvt8(hm[0], hm[1]);
  bf16x8 hb1 = cvt8(hm[2], hm[3]);

  // ---- double-buffered step inputs ----
  f32x4 zA0, zA1, zA2, zA3, zB0, zB1, zB2, zB3;
  float4 aAl, aAh, aBl, aBh;
  float gA, gB;

  R_LOADS(0, zA, aAl, aAh, gA);

  for (int t = 0; t < TT; t += 2) {
    const int t2 = (t + 2 < TT) ? (t + 2) : (TT - 1);  // clamp (redundant reload)
    R_LOADS(t + 1, zB, aBl, aBh, gB);
    R_COMPUTE(t, zA0, zA1, zA2, zA3, aAl, aAh, gA);
    R_LOADS(t2, zA, aAl, aAh, gA);
    R_COMPUTE(t + 1, zB0, zB1, zB2, zB3, aBl, aBh, gB);
  }

#pragma unroll
  for (int m = 0; m < 4; ++m)
    *(f32x4*)(hlast + (size_t)row * HID + 16 * m + 4 * G) = hm[m];
}

extern "C" void kernel_launch(void* const* d_in, const int* in_sizes, int n_in,
                              void* d_out, int out_size, void* d_ws, size_t ws_size,
                              hipStream_t stream) {
  const float* x   = (const float*)d_in[0];
  const float* h0  = (const float*)d_in[1];
  const float* g   = (const float*)d_in[2];
  const float* a   = (const float*)d_in[3];
  const float* Wc1 = (const float*)d_in[4];
  const float* bc1 = (const float*)d_in[5];
  const float* Wc2 = (const float*)d_in[6];
  const float* bc2 = (const float*)d_in[7];
  const float* Wp1 = (const float*)d_in[8];
  const float* bp1 = (const float*)d_in[9];
  const float* Wp2 = (const float*)d_in[10];
  const float* bp2 = (const float*)d_in[11];

  float* out   = (float*)d_out;
  float* outs  = out;                                   // [T,B,H]
  float* hlast = out + (size_t)TT * BB * HID;           // [1,B,H]
  float* capt  = hlast + (size_t)BB * HID;              // [T,B,H]
  short* wsw   = (short*)d_ws;                          // 44 KB fragment buffer

  prep_weights<<<dim3(11), dim3(256), 0, stream>>>(Wc1, Wc2, Wp1, Wp2, wsw);
  capture_lds<<<dim3(2048), dim3(256), 0, stream>>>(x, wsw, bc1, bc2, capt);
  recur_mono<<<dim3(BB / 16), dim3(64), 0, stream>>>(h0, g, a, wsw, bp1, bp2,
                                                     capt, outs, hlast);
}

// Round 14
// 221.443 us; speedup vs baseline: 1.0476x; 1.0476x over previous
//
#include <hip/hip_runtime.h>

#define OBS 128
#define HID 64
#define ACT 32
#define TT  128
#define BB  4096

typedef __attribute__((ext_vector_type(8))) short bf16x8;  // 8 bf16 (4 VGPRs)
typedef __attribute__((ext_vector_type(4))) float f32x4;

// tanh(v) = 1 - 2/(exp(2v)+1); exact at +-inf, ~1e-6 rel error (v_exp + v_rcp)
__device__ __forceinline__ float fast_tanh(float v) {
  const float e = __expf(2.0f * v);
  return 1.0f - 2.0f * __builtin_amdgcn_rcpf(e + 1.0f);
}

// f32 -> bf16 bits, round-to-nearest-even (inputs finite; no NaN path needed)
__device__ __forceinline__ short f2bf(float f) {
  const unsigned u = __float_as_uint(f);
  return (short)((u + 0x7FFFu + ((u >> 16) & 1u)) >> 16);
}

// pack two f32x4 (C/D-layout register quads) into one bf16x8 B-fragment
__device__ __forceinline__ bf16x8 pack2(const f32x4 s0, const f32x4 s1) {
  bf16x8 f;
  f[0] = f2bf(s0[0]); f[1] = f2bf(s0[1]); f[2] = f2bf(s0[2]); f[3] = f2bf(s0[3]);
  f[4] = f2bf(s1[0]); f[5] = f2bf(s1[1]); f[6] = f2bf(s1[2]); f[7] = f2bf(s1[3]);
  return f;
}

// ---------------------------------------------------------------------------
// Prep: fragment-ordered bf16 weight table in d_ws (capture uses frags 0..23;
// recur gathers its weights directly — the r4-verbatim form below).
// ---------------------------------------------------------------------------
__global__ void prep_weights(const float* __restrict__ Wc1,
                             const float* __restrict__ Wc2,
                             const float* __restrict__ Wp1,
                             const float* __restrict__ Wp2,
                             short* __restrict__ ws)
{
  const int idx = blockIdx.x * blockDim.x + threadIdx.x;  // 0..(44*64-1)
  if (idx >= 44 * 64) return;
  const int f = idx >> 6, lane = idx & 63;
  const int r = lane & 15, G = lane >> 4;
  short o[8];
  if (f < 16) {
    const int m = f >> 2, kk = f & 3;  // std: k = 32kk + 8G + j
#pragma unroll
    for (int j = 0; j < 8; ++j)
      o[j] = f2bf(Wc1[(kk * 32 + 8 * G + j) * HID + 16 * m + r]);
  } else if (f < 40) {
    const int q = (f < 24) ? (f - 16) : (f < 32) ? (f - 24) : (f - 32);
    const float* W = (f < 24) ? Wc2 : (f < 32) ? Wp1 : Wp2;
    const int m = q >> 1, kk = q & 1;  // custom k-map (matches lane-resident C/D)
#pragma unroll
    for (int j = 0; j < 8; ++j) {
      const int k = (j < 4) ? (32 * kk + 4 * G + j)
                            : (32 * kk + 16 + 4 * G + (j - 4));
      o[j] = f2bf(W[k * HID + 16 * m + r]);
    }
  } else {
    const int m = f - 40;  // a-part, std map: k = HID + 8G + j
#pragma unroll
    for (int j = 0; j < 8; ++j)
      o[j] = f2bf(Wp1[(HID + 8 * G + j) * HID + 16 * m + r]);
  }
  bf16x8 v;
#pragma unroll
  for (int j = 0; j < 8; ++j) v[j] = o[j];
  *(bf16x8*)(ws + (size_t)idx * 8) = v;
}

// ---------------------------------------------------------------------------
// Phase 1: capture — BYTE-IDENTICAL to rounds 9/12 (deterministic LDS-weight
// form, HBM-bound ~65-75 us at 2 blocks/CU).
// ---------------------------------------------------------------------------
__global__ __launch_bounds__(256, 2) void capture_lds(
    const float* __restrict__ x,
    const short* __restrict__ wsw,
    const float* __restrict__ bc1, const float* __restrict__ bc2,
    float* __restrict__ capt)
{
  __shared__ bf16x8 wl[24 * 64];  // 24.5 KB fragment table

  const int tid  = threadIdx.x;
  const int lane = tid & 63;
  const int r    = lane & 15;   // tile-row (N dim)
  const int G    = lane >> 4;   // k-group
  const int wave = blockIdx.x * 4 + (tid >> 6);
  const int nwaves = gridDim.x * 4;

  // stage fragment table (coalesced 16 B/thread x 6 iters)
  for (int s = tid; s < 24 * 64; s += 256)
    wl[s] = ((const bf16x8*)wsw)[s];
  __syncthreads();

  f32x4 bias1[4], bias2[4];
#pragma unroll
  for (int m = 0; m < 4; ++m) {
    bias1[m] = *(const f32x4*)(bc1 + 16 * m + 4 * G);
    bias2[m] = *(const f32x4*)(bc2 + 16 * m + 4 * G);
  }

  for (int tile = wave; tile < (TT * BB) / 16; tile += nwaves) {
    // structural fence: weight ds_reads cannot be hoisted/CSE'd across
    // iterations -> per-iter LDS reads, deterministic codegen
    asm volatile("" ::: "memory");

    const float* xrow = x + ((size_t)tile * 16 + r) * OBS;
    bf16x8 xa[4];
#pragma unroll
    for (int kk = 0; kk < 4; ++kk) {
      const float4 lo = *(const float4*)(xrow + kk * 32 + 8 * G);
      const float4 hi = *(const float4*)(xrow + kk * 32 + 8 * G + 4);
      bf16x8 f;
      f[0] = f2bf(lo.x); f[1] = f2bf(lo.y); f[2] = f2bf(lo.z); f[3] = f2bf(lo.w);
      f[4] = f2bf(hi.x); f[5] = f2bf(hi.y); f[6] = f2bf(hi.z); f[7] = f2bf(hi.w);
      xa[kk] = f;
    }

    float um[4][4];
#pragma unroll
    for (int m = 0; m < 4; ++m) {
      f32x4 acc = bias1[m];
#pragma unroll
      for (int kk = 0; kk < 4; ++kk)
        acc = __builtin_amdgcn_mfma_f32_16x16x32_bf16(wl[(m * 4 + kk) * 64 + lane],
                                                      xa[kk], acc, 0, 0, 0);
#pragma unroll
      for (int q = 0; q < 4; ++q) um[m][q] = fast_tanh(acc[q]);
    }

    bf16x8 b2[2];
#pragma unroll
    for (int kk = 0; kk < 2; ++kk) {
      bf16x8 f;
#pragma unroll
      for (int j = 0; j < 4; ++j) f[j]     = f2bf(um[2 * kk][j]);
#pragma unroll
      for (int j = 0; j < 4; ++j) f[4 + j] = f2bf(um[2 * kk + 1][j]);
      b2[kk] = f;
    }

    float* crow = capt + ((size_t)tile * 16 + r) * HID;
#pragma unroll
    for (int m = 0; m < 4; ++m) {
      f32x4 acc = bias2[m];
#pragma unroll
      for (int kk = 0; kk < 2; ++kk)
        acc = __builtin_amdgcn_mfma_f32_16x16x32_bf16(wl[(16 + m * 2 + kk) * 64 + lane],
                                                      b2[kk], acc, 0, 0, 0);
      float4 o;
      o.x = fast_tanh(acc[0]); o.y = fast_tanh(acc[1]);
      o.z = fast_tanh(acc[2]); o.w = fast_tanh(acc[3]);
      *(float4*)(crow + 16 * m + 4 * G) = o;
    }
  }
}

// ---------------------------------------------------------------------------
// Phase 2: recurrence — VERBATIM round-4 source (the best measured: 77 us).
// Post-mortem of r5/r12: the asm-pin and LDS-fence "fixes" CAUSED the recur
// regressions (they constrain regalloc/scheduler enough to kill the software
// pipeline; r12: VGPR=96, prefetch sunk, 89% stall). The unconstrained
// monolith lets the compiler keep the 1-deep prefetch live and remat the
// (L2-resident) weight gathers as it sees fit. No pins, no fences, no LDS.
// ---------------------------------------------------------------------------
#define R_LOADS(t, Z, AL, AH, GV)                                   \
  do {                                                              \
    const size_t rb = (size_t)(t) * BB + row;                       \
    const float* zp = z1buf + rb * HID;                             \
    Z##0 = *(const f32x4*)(zp + 4 * G);                             \
    Z##1 = *(const f32x4*)(zp + 16 + 4 * G);                        \
    Z##2 = *(const f32x4*)(zp + 32 + 4 * G);                        \
    Z##3 = *(const f32x4*)(zp + 48 + 4 * G);                        \
    const float* ap = a + rb * ACT + 8 * G;                         \
    AL = *(const float4*)(ap);                                      \
    AH = *(const float4*)(ap + 4);                                  \
    GV = g[rb];                                                     \
  } while (0)

#define R_COMPUTE(t, Z0, Z1, Z2, Z3, AL, AH, GV)                               \
  do {                                                                         \
    bf16x8 ab;                                                                 \
    ab[0] = f2bf(AL.x); ab[1] = f2bf(AL.y); ab[2] = f2bf(AL.z);                \
    ab[3] = f2bf(AL.w); ab[4] = f2bf(AH.x); ab[5] = f2bf(AH.y);                \
    ab[6] = f2bf(AH.z); ab[7] = f2bf(AH.w);                                    \
    f32x4 um[4];                                                               \
    _Pragma("unroll")                                                          \
    for (int m = 0; m < 4; ++m) {                                              \
      f32x4 acc = bias1[m];                                                    \
      acc = __builtin_amdgcn_mfma_f32_16x16x32_bf16(w1h[m][0], hb0, acc, 0, 0, 0); \
      acc = __builtin_amdgcn_mfma_f32_16x16x32_bf16(w1h[m][1], hb1, acc, 0, 0, 0); \
      acc = __builtin_amdgcn_mfma_f32_16x16x32_bf16(w1a[m], ab, acc, 0, 0, 0); \
      f32x4 u;                                                                 \
      u[0] = fast_tanh(acc[0]); u[1] = fast_tanh(acc[1]);                      \
      u[2] = fast_tanh(acc[2]); u[3] = fast_tanh(acc[3]);                      \
      um[m] = u;                                                               \
    }                                                                          \
    const bf16x8 ub0 = pack2(um[0], um[1]);                                    \
    const bf16x8 ub1 = pack2(um[2], um[3]);                                    \
    const size_t ob = ((size_t)(t) * BB + row) * HID;                          \
    _Pragma("unroll")                                                          \
    for (int m = 0; m < 4; ++m) {                                              \
      f32x4 acc = bias2[m];                                                    \
      acc = __builtin_amdgcn_mfma_f32_16x16x32_bf16(w2t[m][0], ub0, acc, 0, 0, 0); \
      acc = __builtin_amdgcn_mfma_f32_16x16x32_bf16(w2t[m][1], ub1, acc, 0, 0, 0); \
      const f32x4 zz = (m == 0) ? Z0 : (m == 1) ? Z1 : (m == 2) ? Z2 : Z3;     \
      f32x4 hn;                                                                \
      hn[0] = fmaf(GV, fast_tanh(acc[0]) - zz[0], zz[0]);                      \
      hn[1] = fmaf(GV, fast_tanh(acc[1]) - zz[1], zz[1]);                      \
      hn[2] = fmaf(GV, fast_tanh(acc[2]) - zz[2], zz[2]);                      \
      hn[3] = fmaf(GV, fast_tanh(acc[3]) - zz[3], zz[3]);                      \
      hm[m] = hn;                                                              \
      *(f32x4*)(outs + ob + 16 * m + 4 * G) = hn;                              \
    }                                                                          \
    hb0 = pack2(hm[0], hm[1]);                                                 \
    hb1 = pack2(hm[2], hm[3]);                                                 \
  } while (0)

__global__ __launch_bounds__(64, 1) void recur_mfma(
    const float* __restrict__ h0,
    const float* __restrict__ g,
    const float* __restrict__ a,
    const float* __restrict__ Wp1, const float* __restrict__ bp1,
    const float* __restrict__ Wp2, const float* __restrict__ bp2,
    const float* __restrict__ z1buf,
    float* __restrict__ outs, float* __restrict__ hlast)
{
  const int lane = threadIdx.x & 63;
  const int r    = lane & 15;
  const int G    = lane >> 4;
  const int row  = blockIdx.x * 16 + r;   // batch row owned by this lane

  // ---- weight fragments (direct gather; compiler free to remat) ----
  bf16x8 w1h[4][2], w2t[4][2], w1a[4];
#pragma unroll
  for (int m = 0; m < 4; ++m) {
#pragma unroll
    for (int kk = 0; kk < 2; ++kk) {
      bf16x8 f1, f2;
#pragma unroll
      for (int j = 0; j < 8; ++j) {
        const int k = (j < 4) ? (32 * kk + 4 * G + j)
                              : (32 * kk + 16 + 4 * G + (j - 4));
        f1[j] = f2bf(Wp1[k * HID + 16 * m + r]);
        f2[j] = f2bf(Wp2[k * HID + 16 * m + r]);
      }
      w1h[m][kk] = f1;
      w2t[m][kk] = f2;
    }
    bf16x8 fa;  // a-part, standard map: k = HID + 8G + j
#pragma unroll
    for (int j = 0; j < 8; ++j)
      fa[j] = f2bf(Wp1[(HID + 8 * G + j) * HID + 16 * m + r]);
    w1a[m] = fa;
  }
  f32x4 bias1[4], bias2[4];
#pragma unroll
  for (int m = 0; m < 4; ++m) {
    bias1[m] = *(const f32x4*)(bp1 + 16 * m + 4 * G);
    bias2[m] = *(const f32x4*)(bp2 + 16 * m + 4 * G);
  }

  // ---- h state in C/D layout ----
  f32x4 hm[4];
#pragma unroll
  for (int m = 0; m < 4; ++m)
    hm[m] = *(const f32x4*)(h0 + (size_t)row * HID + 16 * m + 4 * G);
  bf16x8 hb0 = pack2(hm[0], hm[1]);
  bf16x8 hb1 = pack2(hm[2], hm[3]);

  // ---- double-buffered step inputs ----
  f32x4 zA0, zA1, zA2, zA3, zB0, zB1, zB2, zB3;
  float4 aAl, aAh, aBl, aBh;
  float gA, gB;

  R_LOADS(0, zA, aAl, aAh, gA);

  for (int t = 0; t < TT; t += 2) {
    const int t2 = (t + 2 < TT) ? (t + 2) : (TT - 1);  // clamp (redundant reload)
    R_LOADS(t + 1, zB, aBl, aBh, gB);
    R_COMPUTE(t, zA0, zA1, zA2, zA3, aAl, aAh, gA);
    R_LOADS(t2, zA, aAl, aAh, gA);
    R_COMPUTE(t + 1, zB0, zB1, zB2, zB3, aBl, aBh, gB);
  }

#pragma unroll
  for (int m = 0; m < 4; ++m)
    *(f32x4*)(hlast + (size_t)row * HID + 16 * m + 4 * G) = hm[m];
}

extern "C" void kernel_launch(void* const* d_in, const int* in_sizes, int n_in,
                              void* d_out, int out_size, void* d_ws, size_t ws_size,
                              hipStream_t stream) {
  const float* x   = (const float*)d_in[0];
  const float* h0  = (const float*)d_in[1];
  const float* g   = (const float*)d_in[2];
  const float* a   = (const float*)d_in[3];
  const float* Wc1 = (const float*)d_in[4];
  const float* bc1 = (const float*)d_in[5];
  const float* Wc2 = (const float*)d_in[6];
  const float* bc2 = (const float*)d_in[7];
  const float* Wp1 = (const float*)d_in[8];
  const float* bp1 = (const float*)d_in[9];
  const float* Wp2 = (const float*)d_in[10];
  const float* bp2 = (const float*)d_in[11];

  float* out   = (float*)d_out;
  float* outs  = out;                                   // [T,B,H]
  float* hlast = out + (size_t)TT * BB * HID;           // [1,B,H]
  float* capt  = hlast + (size_t)BB * HID;              // [T,B,H]
  short* wsw   = (short*)d_ws;                          // 44 KB fragment buffer

  prep_weights<<<dim3(11), dim3(256), 0, stream>>>(Wc1, Wc2, Wp1, Wp2, wsw);
  capture_lds<<<dim3(2048), dim3(256), 0, stream>>>(x, wsw, bc1, bc2, capt);
  recur_mfma<<<dim3(BB / 16), dim3(64), 0, stream>>>(h0, g, a, Wp1, bp1, Wp2, bp2,
                                                     capt, outs, hlast);
}

// Round 15
// 214.935 us; speedup vs baseline: 1.0794x; 1.0303x over previous
//
#include <hip/hip_runtime.h>

#define OBS 128
#define HID 64
#define ACT 32
#define TT  128
#define BB  4096

typedef __attribute__((ext_vector_type(8))) short bf16x8;  // 8 bf16 (4 VGPRs)
typedef __attribute__((ext_vector_type(4))) float f32x4;

// tanh(v) = 1 - 2/(exp(2v)+1); exact at +-inf, ~1e-6 rel error (v_exp + v_rcp)
__device__ __forceinline__ float fast_tanh(float v) {
  const float e = __expf(2.0f * v);
  return 1.0f - 2.0f * __builtin_amdgcn_rcpf(e + 1.0f);
}

// f32 -> bf16 bits, round-to-nearest-even (prep + capture paths)
__device__ __forceinline__ short f2bf(float f) {
  const unsigned u = __float_as_uint(f);
  return (short)((u + 0x7FFFu + ((u >> 16) & 1u)) >> 16);
}

// HW packed f32x2 -> bf16x2 (RNE), gfx950; no builtin -> inline asm (T12/m240).
// Bit-identical to f2bf (both RNE) — validated r12 (absmax unchanged).
__device__ __forceinline__ unsigned cvtpk(float lo, float hi) {
  unsigned r;
  asm("v_cvt_pk_bf16_f32 %0, %1, %2" : "=v"(r) : "v"(lo), "v"(hi));
  return r;
}

// pack two f32x4 (C/D-layout quads) into one bf16x8 B-fragment (4 instrs)
__device__ __forceinline__ bf16x8 cvt8(const f32x4 s0, const f32x4 s1) {
  union { bf16x8 f; unsigned u[4]; } z;
  z.u[0] = cvtpk(s0[0], s0[1]); z.u[1] = cvtpk(s0[2], s0[3]);
  z.u[2] = cvtpk(s1[0], s1[1]); z.u[3] = cvtpk(s1[2], s1[3]);
  return z.f;
}

// pack [float4, float4] -> bf16x8 (a-fragment)
__device__ __forceinline__ bf16x8 cvt8f(const float4 lo, const float4 hi) {
  union { bf16x8 f; unsigned u[4]; } z;
  z.u[0] = cvtpk(lo.x, lo.y); z.u[1] = cvtpk(lo.z, lo.w);
  z.u[2] = cvtpk(hi.x, hi.y); z.u[3] = cvtpk(hi.z, hi.w);
  return z.f;
}

// ---------------------------------------------------------------------------
// Prep: fragment-ordered bf16 weight table in d_ws (capture uses frags 0..23;
// recur gathers its weights directly once at kernel start).
// ---------------------------------------------------------------------------
__global__ void prep_weights(const float* __restrict__ Wc1,
                             const float* __restrict__ Wc2,
                             const float* __restrict__ Wp1,
                             const float* __restrict__ Wp2,
                             short* __restrict__ ws)
{
  const int idx = blockIdx.x * blockDim.x + threadIdx.x;  // 0..(44*64-1)
  if (idx >= 44 * 64) return;
  const int f = idx >> 6, lane = idx & 63;
  const int r = lane & 15, G = lane >> 4;
  short o[8];
  if (f < 16) {
    const int m = f >> 2, kk = f & 3;  // std: k = 32kk + 8G + j
#pragma unroll
    for (int j = 0; j < 8; ++j)
      o[j] = f2bf(Wc1[(kk * 32 + 8 * G + j) * HID + 16 * m + r]);
  } else if (f < 40) {
    const int q = (f < 24) ? (f - 16) : (f < 32) ? (f - 24) : (f - 32);
    const float* W = (f < 24) ? Wc2 : (f < 32) ? Wp1 : Wp2;
    const int m = q >> 1, kk = q & 1;  // custom k-map (matches lane-resident C/D)
#pragma unroll
    for (int j = 0; j < 8; ++j) {
      const int k = (j < 4) ? (32 * kk + 4 * G + j)
                            : (32 * kk + 16 + 4 * G + (j - 4));
      o[j] = f2bf(W[k * HID + 16 * m + r]);
    }
  } else {
    const int m = f - 40;  // a-part, std map: k = HID + 8G + j
#pragma unroll
    for (int j = 0; j < 8; ++j)
      o[j] = f2bf(Wp1[(HID + 8 * G + j) * HID + 16 * m + r]);
  }
  bf16x8 v;
#pragma unroll
  for (int j = 0; j < 8; ++j) v[j] = o[j];
  *(bf16x8*)(ws + (size_t)idx * 8) = v;
}

// ---------------------------------------------------------------------------
// Phase 1: capture — BYTE-IDENTICAL to rounds 9/12/14 (deterministic LDS-
// weight form, HBM-bound ~65-75 us at 2 blocks/CU).
// ---------------------------------------------------------------------------
__global__ __launch_bounds__(256, 2) void capture_lds(
    const float* __restrict__ x,
    const short* __restrict__ wsw,
    const float* __restrict__ bc1, const float* __restrict__ bc2,
    float* __restrict__ capt)
{
  __shared__ bf16x8 wl[24 * 64];  // 24.5 KB fragment table

  const int tid  = threadIdx.x;
  const int lane = tid & 63;
  const int r    = lane & 15;   // tile-row (N dim)
  const int G    = lane >> 4;   // k-group
  const int wave = blockIdx.x * 4 + (tid >> 6);
  const int nwaves = gridDim.x * 4;

  // stage fragment table (coalesced 16 B/thread x 6 iters)
  for (int s = tid; s < 24 * 64; s += 256)
    wl[s] = ((const bf16x8*)wsw)[s];
  __syncthreads();

  f32x4 bias1[4], bias2[4];
#pragma unroll
  for (int m = 0; m < 4; ++m) {
    bias1[m] = *(const f32x4*)(bc1 + 16 * m + 4 * G);
    bias2[m] = *(const f32x4*)(bc2 + 16 * m + 4 * G);
  }

  for (int tile = wave; tile < (TT * BB) / 16; tile += nwaves) {
    // structural fence: weight ds_reads cannot be hoisted/CSE'd across
    // iterations -> per-iter LDS reads, deterministic codegen
    asm volatile("" ::: "memory");

    const float* xrow = x + ((size_t)tile * 16 + r) * OBS;
    bf16x8 xa[4];
#pragma unroll
    for (int kk = 0; kk < 4; ++kk) {
      const float4 lo = *(const float4*)(xrow + kk * 32 + 8 * G);
      const float4 hi = *(const float4*)(xrow + kk * 32 + 8 * G + 4);
      bf16x8 f;
      f[0] = f2bf(lo.x); f[1] = f2bf(lo.y); f[2] = f2bf(lo.z); f[3] = f2bf(lo.w);
      f[4] = f2bf(hi.x); f[5] = f2bf(hi.y); f[6] = f2bf(hi.z); f[7] = f2bf(hi.w);
      xa[kk] = f;
    }

    float um[4][4];
#pragma unroll
    for (int m = 0; m < 4; ++m) {
      f32x4 acc = bias1[m];
#pragma unroll
      for (int kk = 0; kk < 4; ++kk)
        acc = __builtin_amdgcn_mfma_f32_16x16x32_bf16(wl[(m * 4 + kk) * 64 + lane],
                                                      xa[kk], acc, 0, 0, 0);
#pragma unroll
      for (int q = 0; q < 4; ++q) um[m][q] = fast_tanh(acc[q]);
    }

    bf16x8 b2[2];
#pragma unroll
    for (int kk = 0; kk < 2; ++kk) {
      bf16x8 f;
#pragma unroll
      for (int j = 0; j < 4; ++j) f[j]     = f2bf(um[2 * kk][j]);
#pragma unroll
      for (int j = 0; j < 4; ++j) f[4 + j] = f2bf(um[2 * kk + 1][j]);
      b2[kk] = f;
    }

    float* crow = capt + ((size_t)tile * 16 + r) * HID;
#pragma unroll
    for (int m = 0; m < 4; ++m) {
      f32x4 acc = bias2[m];
#pragma unroll
      for (int kk = 0; kk < 2; ++kk)
        acc = __builtin_amdgcn_mfma_f32_16x16x32_bf16(wl[(16 + m * 2 + kk) * 64 + lane],
                                                      b2[kk], acc, 0, 0, 0);
      float4 o;
      o.x = fast_tanh(acc[0]); o.y = fast_tanh(acc[1]);
      o.z = fast_tanh(acc[2]); o.w = fast_tanh(acc[3]);
      *(float4*)(crow + 16 * m + 4 * G) = o;
    }
  }
}

// ---------------------------------------------------------------------------
// Phase 2: recurrence — monolith with IN-LOOP weight pins.
// r5/r12/r14 post-mortem: with pins placed BEFORE the loop (or none), the
// allocator settles at 96-120 VGPRs and sinks the weight gather into the
// t-loop: ~40 KB/wave/step of L1/L2 re-gather with ~10 loads in flight
// -> ~2950 cyc/step (157 us). An asm "+v" pin INSIDE the loop makes each
// fragment a loop-carried opaque value — remat across the back-edge is
// impossible, so 112 weight/bias VGPRs stay genuinely live and the gather
// runs once. 64-thr blocks + launch_bounds(64,1) allow up to 512 VGPRs.
// cvt_pk packing (r12, bit-identical RNE) cuts ~350 VALU instrs/step.
// Grid: 256 blocks x 64 threads; wall time = single-wave critical path.
// ---------------------------------------------------------------------------
#define R_LOADS(t, Z, AL, AH, GV)                                   \
  do {                                                              \
    const size_t rb = (size_t)(t) * BB + row;                       \
    const float* zp = z1buf + rb * HID;                             \
    Z##0 = *(const f32x4*)(zp + 4 * G);                             \
    Z##1 = *(const f32x4*)(zp + 16 + 4 * G);                        \
    Z##2 = *(const f32x4*)(zp + 32 + 4 * G);                        \
    Z##3 = *(const f32x4*)(zp + 48 + 4 * G);                        \
    const float* ap = a + rb * ACT + 8 * G;                         \
    AL = *(const float4*)(ap);                                      \
    AH = *(const float4*)(ap + 4);                                  \
    GV = g[rb];                                                     \
  } while (0)

#define R_COMPUTE(t, Z0, Z1, Z2, Z3, AL, AH, GV)                               \
  do {                                                                         \
    const bf16x8 ab = cvt8f(AL, AH);                                           \
    f32x4 um[4];                                                               \
    _Pragma("unroll")                                                          \
    for (int m = 0; m < 4; ++m) {                                              \
      f32x4 acc = bias1[m];                                                    \
      acc = __builtin_amdgcn_mfma_f32_16x16x32_bf16(w1h[m][0], hb0, acc, 0, 0, 0); \
      acc = __builtin_amdgcn_mfma_f32_16x16x32_bf16(w1h[m][1], hb1, acc, 0, 0, 0); \
      acc = __builtin_amdgcn_mfma_f32_16x16x32_bf16(w1a[m], ab, acc, 0, 0, 0); \
      f32x4 u;                                                                 \
      u[0] = fast_tanh(acc[0]); u[1] = fast_tanh(acc[1]);                      \
      u[2] = fast_tanh(acc[2]); u[3] = fast_tanh(acc[3]);                      \
      um[m] = u;                                                               \
    }                                                                          \
    const bf16x8 ub0 = cvt8(um[0], um[1]);                                     \
    const bf16x8 ub1 = cvt8(um[2], um[3]);                                     \
    const size_t ob = ((size_t)(t) * BB + row) * HID;                          \
    _Pragma("unroll")                                                          \
    for (int m = 0; m < 4; ++m) {                                              \
      f32x4 acc = bias2[m];                                                    \
      acc = __builtin_amdgcn_mfma_f32_16x16x32_bf16(w2t[m][0], ub0, acc, 0, 0, 0); \
      acc = __builtin_amdgcn_mfma_f32_16x16x32_bf16(w2t[m][1], ub1, acc, 0, 0, 0); \
      const f32x4 zz = (m == 0) ? Z0 : (m == 1) ? Z1 : (m == 2) ? Z2 : Z3;     \
      f32x4 hn;                                                                \
      hn[0] = fmaf(GV, fast_tanh(acc[0]) - zz[0], zz[0]);                      \
      hn[1] = fmaf(GV, fast_tanh(acc[1]) - zz[1], zz[1]);                      \
      hn[2] = fmaf(GV, fast_tanh(acc[2]) - zz[2], zz[2]);                      \
      hn[3] = fmaf(GV, fast_tanh(acc[3]) - zz[3], zz[3]);                      \
      hm[m] = hn;                                                              \
      *(f32x4*)(outs + ob + 16 * m + 4 * G) = hn;                              \
    }                                                                          \
    hb0 = cvt8(hm[0], hm[1]);                                                  \
    hb1 = cvt8(hm[2], hm[3]);                                                  \
  } while (0)

__global__ __launch_bounds__(64, 1) void recur_mfma(
    const float* __restrict__ h0,
    const float* __restrict__ g,
    const float* __restrict__ a,
    const float* __restrict__ Wp1, const float* __restrict__ bp1,
    const float* __restrict__ Wp2, const float* __restrict__ bp2,
    const float* __restrict__ z1buf,
    float* __restrict__ outs, float* __restrict__ hlast)
{
  const int lane = threadIdx.x & 63;
  const int r    = lane & 15;
  const int G    = lane >> 4;
  const int row  = blockIdx.x * 16 + r;   // batch row owned by this lane

  // ---- weight fragments: gathered ONCE (in-loop pins keep them resident) ----
  bf16x8 w1h[4][2], w2t[4][2], w1a[4];
#pragma unroll
  for (int m = 0; m < 4; ++m) {
#pragma unroll
    for (int kk = 0; kk < 2; ++kk) {
      bf16x8 f1, f2;
#pragma unroll
      for (int j = 0; j < 8; ++j) {
        const int k = (j < 4) ? (32 * kk + 4 * G + j)
                              : (32 * kk + 16 + 4 * G + (j - 4));
        f1[j] = f2bf(Wp1[k * HID + 16 * m + r]);
        f2[j] = f2bf(Wp2[k * HID + 16 * m + r]);
      }
      w1h[m][kk] = f1;
      w2t[m][kk] = f2;
    }
    bf16x8 fa;  // a-part, standard map: k = HID + 8G + j
#pragma unroll
    for (int j = 0; j < 8; ++j)
      fa[j] = f2bf(Wp1[(HID + 8 * G + j) * HID + 16 * m + r]);
    w1a[m] = fa;
  }
  f32x4 bias1[4], bias2[4];
#pragma unroll
  for (int m = 0; m < 4; ++m) {
    bias1[m] = *(const f32x4*)(bp1 + 16 * m + 4 * G);
    bias2[m] = *(const f32x4*)(bp2 + 16 * m + 4 * G);
  }

  // ---- h state in C/D layout ----
  f32x4 hm[4];
#pragma unroll
  for (int m = 0; m < 4; ++m)
    hm[m] = *(const f32x4*)(h0 + (size_t)row * HID + 16 * m + 4 * G);
  bf16x8 hb0 = cvt8(hm[0], hm[1]);
  bf16x8 hb1 = cvt8(hm[2], hm[3]);

  // ---- double-buffered step inputs ----
  f32x4 zA0, zA1, zA2, zA3, zB0, zB1, zB2, zB3;
  float4 aAl, aAh, aBl, aBh;
  float gA, gB;

  R_LOADS(0, zA, aAl, aAh, gA);

  for (int t = 0; t < TT; t += 2) {
    // IN-LOOP PIN: weights/biases become loop-carried opaque values.
    // The allocator cannot re-materialize their loads across the back-edge,
    // so they stay genuinely VGPR-resident for the whole scan. 0 instrs.
#pragma unroll
    for (int m = 0; m < 4; ++m) {
      asm volatile("" : "+v"(w1h[m][0]), "+v"(w1h[m][1]));
      asm volatile("" : "+v"(w2t[m][0]), "+v"(w2t[m][1]));
      asm volatile("" : "+v"(w1a[m]));
      asm volatile("" : "+v"(bias1[m]), "+v"(bias2[m]));
    }

    const int t2 = (t + 2 < TT) ? (t + 2) : (TT - 1);  // clamp (redundant reload)
    R_LOADS(t + 1, zB, aBl, aBh, gB);
    R_COMPUTE(t, zA0, zA1, zA2, zA3, aAl, aAh, gA);
    R_LOADS(t2, zA, aAl, aAh, gA);
    R_COMPUTE(t + 1, zB0, zB1, zB2, zB3, aBl, aBh, gB);
  }

#pragma unroll
  for (int m = 0; m < 4; ++m)
    *(f32x4*)(hlast + (size_t)row * HID + 16 * m + 4 * G) = hm[m];
}

extern "C" void kernel_launch(void* const* d_in, const int* in_sizes, int n_in,
                              void* d_out, int out_size, void* d_ws, size_t ws_size,
                              hipStream_t stream) {
  const float* x   = (const float*)d_in[0];
  const float* h0  = (const float*)d_in[1];
  const float* g   = (const float*)d_in[2];
  const float* a   = (const float*)d_in[3];
  const float* Wc1 = (const float*)d_in[4];
  const float* bc1 = (const float*)d_in[5];
  const float* Wc2 = (const float*)d_in[6];
  const float* bc2 = (const float*)d_in[7];
  const float* Wp1 = (const float*)d_in[8];
  const float* bp1 = (const float*)d_in[9];
  const float* Wp2 = (const float*)d_in[10];
  const float* bp2 = (const float*)d_in[11];

  float* out   = (float*)d_out;
  float* outs  = out;                                   // [T,B,H]
  float* hlast = out + (size_t)TT * BB * HID;           // [1,B,H]
  float* capt  = hlast + (size_t)BB * HID;              // [T,B,H]
  short* wsw   = (short*)d_ws;                          // 44 KB fragment buffer

  prep_weights<<<dim3(11), dim3(256), 0, stream>>>(Wc1, Wc2, Wp1, Wp2, wsw);
  capture_lds<<<dim3(2048), dim3(256), 0, stream>>>(x, wsw, bc1, bc2, capt);
  recur_mfma<<<dim3(BB / 16), dim3(64), 0, stream>>>(h0, g, a, Wp1, bp1, Wp2, bp2,
                                                     capt, outs, hlast);
}